// Round 2
// baseline (480.455 us; speedup 1.0000x reference)
//
#include <hip/hip_runtime.h>
#include <hip/hip_bf16.h>
#include <stdint.h>

// ---------------- problem constants ----------------
#define B_    2
#define L_    2048
#define H_    1024
#define DIN_  2048
#define NST   16
#define RD    64
#define M_    (B_*L_)   // 4096
#define LC    64        // scan chunk length
#define NCH   32        // chunks (LC*NCH == L_)

typedef __attribute__((ext_vector_type(8))) short short8;
typedef __attribute__((ext_vector_type(4))) float f32x4;

// ---------------- helpers ----------------
__device__ inline ushort f2bf(float v) {
  uint32_t u = __float_as_uint(v);
  uint32_t r = (u + 0x7fffu + ((u >> 16) & 1u)) >> 16;
  return (ushort)r;
}
__device__ inline float bf2f(ushort h) { return __uint_as_float(((uint32_t)h) << 16); }

__device__ inline void gload_lds16(const ushort* g, ushort* l) {
  __builtin_amdgcn_global_load_lds((const __attribute__((address_space(1))) void*)g,
                                   (__attribute__((address_space(3))) void*)l, 16, 0, 0);
}

// ---------------- pack fp32 -> [hi(cols) | lo(cols)] bf16 rows ----------------
// out physical layout: (out_rows, 2*cols) ushort; rows >= `rows` are zero-filled.
__global__ __launch_bounds__(256)
void pack_hilo(const float* __restrict__ in, ushort* __restrict__ out,
               int rows, int cols, int in_stride, int out_rows)
{
  int half = cols >> 1;
  int idx = blockIdx.x * 256 + threadIdx.x;
  if (idx >= out_rows * half) return;
  int r = idx / half;
  int c = (idx - r * half) * 2;
  float v0 = 0.f, v1 = 0.f;
  if (r < rows) { const float* p = in + (size_t)r * in_stride + c; v0 = p[0]; v1 = p[1]; }
  ushort h0 = f2bf(v0), h1 = f2bf(v1);
  ushort g0 = f2bf(v0 - bf2f(h0)), g1 = f2bf(v1 - bf2f(h1));
  ushort* orow = out + (size_t)r * (2 * cols);
  *(uint32_t*)(orow + c)        = (uint32_t)h0 | ((uint32_t)h1 << 16);
  *(uint32_t*)(orow + cols + c) = (uint32_t)g0 | ((uint32_t)g1 << 16);
}

// ---------------- split-bf16 GEMM  C[m,n] = sum_k A[m,k]*B[n,k] ----------------
// A,B packed [hi|lo]: physical row stride 2K; logical Kp=3K covers
// hi*hi + lo*hi + hi*lo  (A' = [hi|lo|hi], B' = [hi|hi|lo]).
// EPI: 0 = plain store; 1 = softplus(acc + bias[n])
template<int EPI>
__global__ __launch_bounds__(256, 2)
void gemm_bt(const ushort* __restrict__ A, const ushort* __restrict__ Bw,
             float* __restrict__ C, int M, int N, int K,
             const float* __restrict__ bias)
{
  const int P = 2 * K;          // physical stride
  const int Kp = 3 * K;         // logical K
  __shared__ ushort sA[2][128 * 32];
  __shared__ ushort sB[2][128 * 32];
  const int tid = threadIdx.x, wid = tid >> 6, lid = tid & 63;
  const size_t m0 = (size_t)blockIdx.x * 128, n0 = (size_t)blockIdx.y * 128;
  int kLen = Kp, kBase = 0;
  if (gridDim.z > 1) { kLen = Kp / gridDim.z; kBase = blockIdx.z * kLen; C += (size_t)blockIdx.z * M * N; }
  const int nIter = kLen / 32;

  const ushort* gA[2]; const ushort* gB[2];
  ushort* lA[2]; ushort* lB[2];
#pragma unroll
  for (int t = 0; t < 2; ++t) {
    int j = wid * 2 + t;
    gA[t] = A  + (size_t)(m0 + j * 16 + (lid >> 2)) * P + (lid & 3) * 8;
    gB[t] = Bw + (size_t)(n0 + j * 16 + (lid >> 2)) * P + (lid & 3) * 8;
    lA[t] = &sA[0][j * 512];
    lB[t] = &sB[0][j * 512];
  }

  f32x4 acc[4][4];
#pragma unroll
  for (int i = 0; i < 4; ++i)
#pragma unroll
    for (int j = 0; j < 4; ++j) acc[i][j] = (f32x4){0.f, 0.f, 0.f, 0.f};

  // prologue: stage iter 0 into buf 0
  {
    int kk = kBase;
    int kA = kk < P ? kk : kk - P;        // A' = [hi | lo | hi]
    int kB = kk < K ? kk : kk - K;        // B' = [hi | hi | lo]
#pragma unroll
    for (int t = 0; t < 2; ++t) { gload_lds16(gA[t] + kA, lA[t]); gload_lds16(gB[t] + kB, lB[t]); }
  }

  const int wr = wid >> 1, wc = wid & 1;
  const int arow = wr * 64 + (lid & 15), brow = wc * 64 + (lid & 15);
  const int fofs = (lid >> 4) * 8;
  int buf = 0;
  for (int it = 0; it < nIter; ++it) {
    __syncthreads();                       // staged buf ready; prev reads drained
    if (it + 1 < nIter) {
      int kk = kBase + (it + 1) * 32;
      int kA = kk < P ? kk : kk - P;
      int kB = kk < K ? kk : kk - K;
      int nb = buf ^ 1;
#pragma unroll
      for (int t = 0; t < 2; ++t) {
        gload_lds16(gA[t] + kA, lA[t] + nb * 4096);
        gload_lds16(gB[t] + kB, lB[t] + nb * 4096);
      }
    }
    short8 af[4], bfr[4];
    const ushort* pa = &sA[buf][arow * 32 + fofs];
    const ushort* pb = &sB[buf][brow * 32 + fofs];
#pragma unroll
    for (int i = 0; i < 4; ++i) af[i] = *(const short8*)(pa + i * 16 * 32);
#pragma unroll
    for (int j = 0; j < 4; ++j) bfr[j] = *(const short8*)(pb + j * 16 * 32);
#pragma unroll
    for (int i = 0; i < 4; ++i)
#pragma unroll
      for (int j = 0; j < 4; ++j)
        acc[i][j] = __builtin_amdgcn_mfma_f32_16x16x32_bf16(af[i], bfr[j], acc[i][j], 0, 0, 0);
    buf ^= 1;
  }

  const int crow = (lid >> 4) * 4, ccol = lid & 15;
#pragma unroll
  for (int i = 0; i < 4; ++i) {
    size_t row = m0 + wr * 64 + i * 16 + crow;
#pragma unroll
    for (int j = 0; j < 4; ++j) {
      size_t col = n0 + wc * 64 + j * 16 + ccol;
#pragma unroll
      for (int r = 0; r < 4; ++r) {
        float v = acc[i][j][r];
        if (EPI == 1) { v += bias[col]; v = (v > 20.f) ? v : __logf(1.f + __expf(v)); }
        C[(row + r) * N + col] = v;
      }
    }
  }
}

// ---------------- causal depthwise conv (K=4) + SiLU + hi/lo pack ----------------
#define CONV_LT 8
__global__ __launch_bounds__(256)
void conv_silu_pack(const float* __restrict__ hs_res, const float* __restrict__ w_conv,
                    ushort* __restrict__ hsc_pk)
{
  const int d = blockIdx.x * 256 + threadIdx.x;
  const int l0 = blockIdx.y * CONV_LT;
  const int b = blockIdx.z;
  const float w0 = w_conv[d * 4 + 0], w1 = w_conv[d * 4 + 1];
  const float w2 = w_conv[d * 4 + 2], w3 = w_conv[d * 4 + 3];
  const float* in = hs_res + (size_t)(b * L_) * 4096 + d;   // first half of hs_res row
  float a0 = 0.f, a1 = 0.f, a2 = 0.f;
  if (l0 > 0) {
    a0 = in[(size_t)(l0 - 3) * 4096];
    a1 = in[(size_t)(l0 - 2) * 4096];
    a2 = in[(size_t)(l0 - 1) * 4096];
  }
#pragma unroll
  for (int t = 0; t < CONV_LT; ++t) {
    int l = l0 + t;
    float x = in[(size_t)l * 4096];
    float v = fmaf(w0, a0, fmaf(w1, a1, fmaf(w2, a2, w3 * x)));
    v = v / (1.f + __expf(-v));           // SiLU
    size_t m = (size_t)b * L_ + l;
    ushort hi = f2bf(v), lo = f2bf(v - bf2f(hi));
    hsc_pk[m * 4096 + d] = hi;
    hsc_pk[m * 4096 + 2048 + d] = lo;
    a0 = a1; a1 = a2; a2 = x;
  }
}

// ---------------- reduce split-K partials of x_dbl + pack dt cols ----------------
__global__ __launch_bounds__(256)
void reduce_xdbl(const float* __restrict__ part, float* __restrict__ x_dbl,
                 ushort* __restrict__ dt_pk)
{
  int i = blockIdx.x * 256 + threadIdx.x;   // < 4096*128
  float s = 0.f;
#pragma unroll
  for (int z = 0; z < 8; ++z) s += part[(size_t)z * (M_ * 128) + i];
  x_dbl[i] = s;
  int c = i & 127, r = i >> 7;
  if (c < 64) {
    ushort hi = f2bf(s), lo = f2bf(s - bf2f(hi));
    dt_pk[(size_t)r * 128 + c] = hi;
    dt_pk[(size_t)r * 128 + 64 + c] = lo;
  }
}

// ---------------- selective scan, chunked two-pass ----------------
// x is reconstructed from the packed hi/lo bf16 tensor (error ~2^-17).
__global__ __launch_bounds__(256)
void scan_pass1(const ushort* __restrict__ hsc_pk, const float* __restrict__ delta,
                const float* __restrict__ x_dbl, const float* __restrict__ A_log,
                float* __restrict__ Pbuf, float* __restrict__ Qbuf)
{
  __shared__ float sBC[LC * 32];
  const int d = blockIdx.x * 256 + threadIdx.x;
  const int c = blockIdx.y, b = blockIdx.z;
  const int l0 = c * LC;
#pragma unroll
  for (int q = 0; q < 8; ++q) {
    int f = threadIdx.x + 256 * q;          // f = lr*32 + nn
    int lr = f >> 5, nn = f & 31;
    sBC[f] = x_dbl[((size_t)(b * L_ + l0 + lr)) * 128 + 64 + nn];
  }
  float An[NST];
#pragma unroll
  for (int n = 0; n < NST; ++n) An[n] = -__expf(A_log[(size_t)d * 16 + n]);
  float z[NST], Pp[NST];
#pragma unroll
  for (int n = 0; n < NST; ++n) { z[n] = 0.f; Pp[n] = 1.f; }
  __syncthreads();
  const float*  dp = delta  + (size_t)(b * L_ + l0) * 2048 + d;
  const ushort* xp = hsc_pk + (size_t)(b * L_ + l0) * 4096 + d;
  for (int t = 0; t < LC; ++t) {
    float dl = dp[(size_t)t * 2048];
    float xv = bf2f(xp[(size_t)t * 4096]) + bf2f(xp[(size_t)t * 4096 + 2048]);
    float dx = dl * xv;
    const float* bc = &sBC[t * 32];
#pragma unroll
    for (int n = 0; n < NST; ++n) {
      float dA = __expf(dl * An[n]);
      z[n] = fmaf(dA, z[n], dx * bc[n]);
      Pp[n] *= dA;
    }
  }
  size_t base = ((size_t)(b * NCH + c) * 16) * 2048 + d;
#pragma unroll
  for (int n = 0; n < NST; ++n) {
    Pbuf[base + (size_t)n * 2048] = Pp[n];
    Qbuf[base + (size_t)n * 2048] = z[n];
  }
}

__global__ __launch_bounds__(256)
void scan_combine(const float* __restrict__ Pbuf, const float* __restrict__ Qbuf,
                  float* __restrict__ zinit)
{
  int i = blockIdx.x * 256 + threadIdx.x;   // B_*16*2048 = 65536
  int d = i & 2047, n = (i >> 11) & 15, b = i >> 15;
  float z = 0.f;
  for (int c = 0; c < NCH; ++c) {
    size_t idx = ((size_t)(b * NCH + c) * 16 + n) * 2048 + d;
    zinit[idx] = z;
    z = fmaf(Pbuf[idx], z, Qbuf[idx]);
  }
}

// pass2 overwrites hsc_pk in place with packed y (same thread, same addresses,
// read-before-write within each t iteration -> race-free by program order).
__global__ __launch_bounds__(256)
void scan_pass2(ushort* __restrict__ hsc_pk, const float* __restrict__ delta,
                const float* __restrict__ x_dbl, const float* __restrict__ A_log,
                const float* __restrict__ zinit, const float* __restrict__ Dvec,
                const float* __restrict__ hs_res)
{
  __shared__ float sBC[LC * 32];
  const int d = blockIdx.x * 256 + threadIdx.x;
  const int c = blockIdx.y, b = blockIdx.z;
  const int l0 = c * LC;
#pragma unroll
  for (int q = 0; q < 8; ++q) {
    int f = threadIdx.x + 256 * q;
    int lr = f >> 5, nn = f & 31;
    sBC[f] = x_dbl[((size_t)(b * L_ + l0 + lr)) * 128 + 64 + nn];
  }
  float An[NST];
#pragma unroll
  for (int n = 0; n < NST; ++n) An[n] = -__expf(A_log[(size_t)d * 16 + n]);
  float z[NST];
  size_t zb = ((size_t)(b * NCH + c) * 16) * 2048 + d;
#pragma unroll
  for (int n = 0; n < NST; ++n) z[n] = zinit[zb + (size_t)n * 2048];
  const float Dd = Dvec[d];
  __syncthreads();
  const float* dp = delta  + (size_t)(b * L_ + l0) * 2048 + d;
  ushort*      xp = hsc_pk + (size_t)(b * L_ + l0) * 4096 + d;
  const float* rp = hs_res + (size_t)(b * L_ + l0) * 4096 + 2048 + d;   // res half
  for (int t = 0; t < LC; ++t) {
    float dl = dp[(size_t)t * 2048];
    float xv = bf2f(xp[(size_t)t * 4096]) + bf2f(xp[(size_t)t * 4096 + 2048]);
    float dx = dl * xv;
    const float* bc = &sBC[t * 32];
    float y = 0.f;
#pragma unroll
    for (int n = 0; n < NST; ++n) {
      float dA = __expf(dl * An[n]);
      z[n] = fmaf(dA, z[n], dx * bc[n]);
      y = fmaf(z[n], bc[16 + n], y);
    }
    y = fmaf(xv, Dd, y);
    float rv = rp[(size_t)t * 4096];
    y *= rv / (1.f + __expf(-rv));        // * silu(res)
    ushort hi = f2bf(y), lo = f2bf(y - bf2f(hi));
    xp[(size_t)t * 4096] = hi;            // y_pk aliases hsc_pk (in place)
    xp[(size_t)t * 4096 + 2048] = lo;
  }
}

// ---------------- launch ----------------
extern "C" void kernel_launch(void* const* d_in, const int* in_sizes, int n_in,
                              void* d_out, int out_size, void* d_ws, size_t ws_size,
                              hipStream_t stream)
{
  (void)in_sizes; (void)n_in; (void)out_size; (void)ws_size;
  const float* hidden  = (const float*)d_in[0];
  const float* w_in    = (const float*)d_in[1];
  const float* w_conv  = (const float*)d_in[2];
  const float* w_xproj = (const float*)d_in[3];
  const float* w_dt    = (const float*)d_in[4];
  const float* b_dt    = (const float*)d_in[5];
  const float* A_log   = (const float*)d_in[6];
  const float* Dvec    = (const float*)d_in[7];
  const float* w_out   = (const float*)d_in[8];
  float* out = (float*)d_out;

  // ---- lifetime-aliased arena (peak ~173 MB) ----
  char* ws = (char*)d_ws;
  size_t off = 0;
  auto alloc = [&](size_t bytes) -> char* {
    char* p = ws + off; off += (bytes + 255) & ~(size_t)255; return p;
  };
  ushort* w_out_pk = (ushort*)alloc((size_t)1024 * 4096 * 2);   //  8 MB, whole call
  float*  hs_res   = (float*) alloc((size_t)4096 * 4096 * 4);   // 64 MB, GEMM1 -> pass2
  ushort* hsc_pk   = (ushort*)alloc((size_t)4096 * 4096 * 2);   // 32 MB, conv -> GEMM3/scans; pass2 rewrites as y_pk
  float*  delta    = (float*) alloc((size_t)4096 * 2048 * 4);   // 32 MB, GEMM4 -> scans
  char*   regA     = alloc((size_t)16 * 1024 * 1024);           // 16 MB: hsin_pk | xdbl_part | Pbuf+Qbuf
  char*   regB     = alloc((size_t)16 * 1024 * 1024);           // 16 MB: w_in_pk | zinit
  ushort* w_xproj_pk = (ushort*)alloc((size_t)128 * 4096 * 2);  //  1 MB
  ushort* w_dt_pk    = (ushort*)alloc((size_t)2048 * 128 * 2);  //  0.5 MB
  ushort* dt_pk      = (ushort*)alloc((size_t)4096 * 128 * 2);  //  1 MB
  float*  x_dbl      = (float*) alloc((size_t)4096 * 128 * 4);  //  2 MB

  ushort* hsin_pk   = (ushort*)regA;                 // pack -> GEMM1
  float*  xdbl_part = (float*)regA;                  // GEMM3 -> reduce
  float*  Pbuf      = (float*)regA;                  // pass1 -> combine
  float*  Qbuf      = (float*)(regA + 8 * 1024 * 1024);
  ushort* w_in_pk   = (ushort*)regB;                 // pack -> GEMM1
  float*  zinit     = (float*)regB;                  // combine -> pass2
  ushort* y_pk      = hsc_pk;                        // pass2 -> GEMM6

  auto packBlocks = [](int out_rows, int cols) { return (out_rows * (cols / 2) + 255) / 256; };

  // packs (weights + activations)
  pack_hilo<<<packBlocks(4096, 1024), 256, 0, stream>>>(hidden, hsin_pk, 4096, 1024, 1024, 4096);
  pack_hilo<<<packBlocks(4096, 1024), 256, 0, stream>>>(w_in, w_in_pk, 4096, 1024, 1024, 4096);
  pack_hilo<<<packBlocks(128, 2048), 256, 0, stream>>>(w_xproj, w_xproj_pk, 96, 2048, 2048, 128);
  pack_hilo<<<packBlocks(2048, 64), 256, 0, stream>>>(w_dt, w_dt_pk, 2048, 64, 64, 2048);
  pack_hilo<<<packBlocks(1024, 2048), 256, 0, stream>>>(w_out, w_out_pk, 1024, 2048, 2048, 1024);

  // 1) hs_res = hidden @ w_in^T   (M=4096, N=4096, K=1024)
  gemm_bt<0><<<dim3(32, 32, 1), 256, 0, stream>>>(hsin_pk, w_in_pk, hs_res, 4096, 4096, 1024, nullptr);

  // 2) conv + silu + pack
  conv_silu_pack<<<dim3(8, L_ / CONV_LT, B_), 256, 0, stream>>>(hs_res, w_conv, hsc_pk);

  // 3) x_dbl = hs @ w_xproj^T  (split-K=8 into partials, then reduce + pack dt)
  gemm_bt<0><<<dim3(32, 1, 8), 256, 0, stream>>>(hsc_pk, w_xproj_pk, xdbl_part, 4096, 128, 2048, nullptr);
  reduce_xdbl<<<(4096 * 128) / 256, 256, 0, stream>>>(xdbl_part, x_dbl, dt_pk);

  // 4) delta = softplus(dt @ w_dt^T + b_dt)  (M=4096, N=2048, K=64)
  gemm_bt<1><<<dim3(32, 16, 1), 256, 0, stream>>>(dt_pk, w_dt_pk, delta, 4096, 2048, 64, b_dt);

  // 5) selective scan (two-pass chunked) + gate + pack y (in place over hsc_pk)
  scan_pass1<<<dim3(8, NCH, B_), 256, 0, stream>>>(hsc_pk, delta, x_dbl, A_log, Pbuf, Qbuf);
  scan_combine<<<(B_ * 16 * 2048) / 256, 256, 0, stream>>>(Pbuf, Qbuf, zinit);
  scan_pass2<<<dim3(8, NCH, B_), 256, 0, stream>>>(hsc_pk, delta, x_dbl, A_log, zinit, Dvec, hs_res);

  // 6) out = (y*silu(res)) @ w_out^T  (M=4096, N=1024, K=2048)
  gemm_bt<0><<<dim3(32, 8, 1), 256, 0, stream>>>(y_pk, w_out_pk, out, 4096, 1024, 2048, nullptr);
}

// Round 4
// 465.558 us; speedup vs baseline: 1.0320x; 1.0320x over previous
//
#include <hip/hip_runtime.h>
#include <hip/hip_bf16.h>
#include <stdint.h>

// ---------------- problem constants ----------------
#define B_    2
#define L_    2048
#define H_    1024
#define DIN_  2048
#define NST   16
#define RD    64
#define M_    (B_*L_)   // 4096
#define LC    64        // scan chunk length
#define NCH   32        // chunks (LC*NCH == L_)

typedef __attribute__((ext_vector_type(8))) short short8;
typedef __attribute__((ext_vector_type(4))) float f32x4;

// ---------------- helpers ----------------
__device__ inline ushort f2bf(float v) {
  uint32_t u = __float_as_uint(v);
  uint32_t r = (u + 0x7fffu + ((u >> 16) & 1u)) >> 16;
  return (ushort)r;
}
__device__ inline float bf2f(ushort h) { return __uint_as_float(((uint32_t)h) << 16); }

__device__ inline void gload_lds16(const ushort* g, ushort* l) {
  __builtin_amdgcn_global_load_lds((const __attribute__((address_space(1))) void*)g,
                                   (__attribute__((address_space(3))) void*)l, 16, 0, 0);
}

// ---------------- pack fp32 -> [hi(cols) | lo(cols)] bf16 rows ----------------
__global__ __launch_bounds__(256)
void pack_hilo(const float* __restrict__ in, ushort* __restrict__ out,
               int rows, int cols, int in_stride, int out_rows)
{
  int half = cols >> 1;
  int idx = blockIdx.x * 256 + threadIdx.x;
  if (idx >= out_rows * half) return;
  int r = idx / half;
  int c = (idx - r * half) * 2;
  float v0 = 0.f, v1 = 0.f;
  if (r < rows) { const float* p = in + (size_t)r * in_stride + c; v0 = p[0]; v1 = p[1]; }
  ushort h0 = f2bf(v0), h1 = f2bf(v1);
  ushort g0 = f2bf(v0 - bf2f(h0)), g1 = f2bf(v1 - bf2f(h1));
  ushort* orow = out + (size_t)r * (2 * cols);
  *(uint32_t*)(orow + c)        = (uint32_t)h0 | ((uint32_t)h1 << 16);
  *(uint32_t*)(orow + cols + c) = (uint32_t)g0 | ((uint32_t)g1 << 16);
}

// ---------------- split-bf16 GEMM  C[m,n] = sum_k A[m,k]*B[n,k] ----------------
// A,B packed [hi|lo]: physical row stride 2K; logical Kp=3K covers
// hi*hi + lo*hi + hi*lo  (A' = [hi|lo|hi], B' = [hi|hi|lo]).
// EPI: 0 = plain store; 1 = softplus(acc + bias[n])
template<int EPI>
__global__ __launch_bounds__(256, 4)   // grid-size is the occupancy limiter; allow 4 blocks/CU
void gemm_bt(const ushort* __restrict__ A, const ushort* __restrict__ Bw,
             float* __restrict__ C, int M, int N, int K,
             const float* __restrict__ bias)
{
  const int P = 2 * K;          // physical stride
  const int Kp = 3 * K;         // logical K
  __shared__ ushort sA[2][128 * 32];
  __shared__ ushort sB[2][128 * 32];
  const int tid = threadIdx.x, wid = tid >> 6, lid = tid & 63;
  const size_t m0 = (size_t)blockIdx.x * 128, n0 = (size_t)blockIdx.y * 128;
  int kLen = Kp, kBase = 0;
  if (gridDim.z > 1) { kLen = Kp / gridDim.z; kBase = blockIdx.z * kLen; C += (size_t)blockIdx.z * M * N; }
  const int nIter = kLen / 32;

  const ushort* gA[2]; const ushort* gB[2];
  ushort* lA[2]; ushort* lB[2];
#pragma unroll
  for (int t = 0; t < 2; ++t) {
    int j = wid * 2 + t;
    gA[t] = A  + (size_t)(m0 + j * 16 + (lid >> 2)) * P + (lid & 3) * 8;
    gB[t] = Bw + (size_t)(n0 + j * 16 + (lid >> 2)) * P + (lid & 3) * 8;
    lA[t] = &sA[0][j * 512];
    lB[t] = &sB[0][j * 512];
  }

  f32x4 acc[4][4];
#pragma unroll
  for (int i = 0; i < 4; ++i)
#pragma unroll
    for (int j = 0; j < 4; ++j) acc[i][j] = (f32x4){0.f, 0.f, 0.f, 0.f};

  // prologue: stage iter 0 into buf 0
  {
    int kk = kBase;
    int kA = kk < P ? kk : kk - P;        // A' = [hi | lo | hi]
    int kB = kk < K ? kk : kk - K;        // B' = [hi | hi | lo]
#pragma unroll
    for (int t = 0; t < 2; ++t) { gload_lds16(gA[t] + kA, lA[t]); gload_lds16(gB[t] + kB, lB[t]); }
  }

  const int wr = wid >> 1, wc = wid & 1;
  const int arow = wr * 64 + (lid & 15), brow = wc * 64 + (lid & 15);
  const int fofs = (lid >> 4) * 8;
  int buf = 0;
  for (int it = 0; it < nIter; ++it) {
    __syncthreads();                       // staged buf ready; prev reads drained
    if (it + 1 < nIter) {
      int kk = kBase + (it + 1) * 32;
      int kA = kk < P ? kk : kk - P;
      int kB = kk < K ? kk : kk - K;
      int nb = buf ^ 1;
#pragma unroll
      for (int t = 0; t < 2; ++t) {
        gload_lds16(gA[t] + kA, lA[t] + nb * 4096);
        gload_lds16(gB[t] + kB, lB[t] + nb * 4096);
      }
    }
    short8 af[4], bfr[4];
    const ushort* pa = &sA[buf][arow * 32 + fofs];
    const ushort* pb = &sB[buf][brow * 32 + fofs];
#pragma unroll
    for (int i = 0; i < 4; ++i) af[i] = *(const short8*)(pa + i * 16 * 32);
#pragma unroll
    for (int j = 0; j < 4; ++j) bfr[j] = *(const short8*)(pb + j * 16 * 32);
#pragma unroll
    for (int i = 0; i < 4; ++i)
#pragma unroll
      for (int j = 0; j < 4; ++j)
        acc[i][j] = __builtin_amdgcn_mfma_f32_16x16x32_bf16(af[i], bfr[j], acc[i][j], 0, 0, 0);
    buf ^= 1;
  }

  const int crow = (lid >> 4) * 4, ccol = lid & 15;
#pragma unroll
  for (int i = 0; i < 4; ++i) {
    size_t row = m0 + wr * 64 + i * 16 + crow;
#pragma unroll
    for (int j = 0; j < 4; ++j) {
      size_t col = n0 + wc * 64 + j * 16 + ccol;
#pragma unroll
      for (int r = 0; r < 4; ++r) {
        float v = acc[i][j][r];
        if (EPI == 1) { v += bias[col]; v = (v > 20.f) ? v : __logf(1.f + __expf(v)); }
        C[(row + r) * N + col] = v;
      }
    }
  }
}

// ---------------- 2-way split-K reduce into out (float4) ----------------
__global__ __launch_bounds__(256)
void reduce2_out(const float* __restrict__ part, float* __restrict__ out)
{
  int i = blockIdx.x * 256 + threadIdx.x;   // over 4096*1024/4 float4 = 1M
  const f32x4* p0 = (const f32x4*)part;
  const f32x4* p1 = (const f32x4*)(part + (size_t)M_ * 1024);
  f32x4 a = p0[i], b = p1[i];
  ((f32x4*)out)[i] = (f32x4){a.x + b.x, a.y + b.y, a.z + b.z, a.w + b.w};
}

// ---------------- causal depthwise conv (K=4) + SiLU + hi/lo pack ----------------
#define CONV_LT 8
__global__ __launch_bounds__(256)
void conv_silu_pack(const float* __restrict__ hs_res, const float* __restrict__ w_conv,
                    ushort* __restrict__ hsc_pk)
{
  const int d = blockIdx.x * 256 + threadIdx.x;
  const int l0 = blockIdx.y * CONV_LT;
  const int b = blockIdx.z;
  const float w0 = w_conv[d * 4 + 0], w1 = w_conv[d * 4 + 1];
  const float w2 = w_conv[d * 4 + 2], w3 = w_conv[d * 4 + 3];
  const float* in = hs_res + (size_t)(b * L_) * 4096 + d;   // first half of hs_res row
  float a0 = 0.f, a1 = 0.f, a2 = 0.f;
  if (l0 > 0) {
    a0 = in[(size_t)(l0 - 3) * 4096];
    a1 = in[(size_t)(l0 - 2) * 4096];
    a2 = in[(size_t)(l0 - 1) * 4096];
  }
#pragma unroll
  for (int t = 0; t < CONV_LT; ++t) {
    int l = l0 + t;
    float x = in[(size_t)l * 4096];
    float v = fmaf(w0, a0, fmaf(w1, a1, fmaf(w2, a2, w3 * x)));
    v = v / (1.f + __expf(-v));           // SiLU
    size_t m = (size_t)b * L_ + l;
    ushort hi = f2bf(v), lo = f2bf(v - bf2f(hi));
    hsc_pk[m * 4096 + d] = hi;
    hsc_pk[m * 4096 + 2048 + d] = lo;
    a0 = a1; a1 = a2; a2 = x;
  }
}

// ---------------- reduce split-K(16) partials of x_dbl + pack dt cols ----------------
__global__ __launch_bounds__(256)
void reduce_xdbl(const float* __restrict__ part, float* __restrict__ x_dbl,
                 ushort* __restrict__ dt_pk)
{
  int i = blockIdx.x * 256 + threadIdx.x;   // < 4096*128
  float s = 0.f;
#pragma unroll
  for (int z = 0; z < 16; ++z) s += part[(size_t)z * (M_ * 128) + i];
  x_dbl[i] = s;
  int c = i & 127, r = i >> 7;
  if (c < 64) {
    ushort hi = f2bf(s), lo = f2bf(s - bf2f(hi));
    dt_pk[(size_t)r * 128 + c] = hi;
    dt_pk[(size_t)r * 128 + 64 + c] = lo;
  }
}

// ---------------- selective scan, chunked two-pass ----------------
__global__ __launch_bounds__(256)
void scan_pass1(const ushort* __restrict__ hsc_pk, const float* __restrict__ delta,
                const float* __restrict__ x_dbl, const float* __restrict__ A_log,
                float* __restrict__ Pbuf, float* __restrict__ Qbuf)
{
  __shared__ float sBC[LC * 32];
  const int d = blockIdx.x * 256 + threadIdx.x;
  const int c = blockIdx.y, b = blockIdx.z;
  const int l0 = c * LC;
#pragma unroll
  for (int q = 0; q < 8; ++q) {
    int f = threadIdx.x + 256 * q;          // f = lr*32 + nn
    int lr = f >> 5, nn = f & 31;
    sBC[f] = x_dbl[((size_t)(b * L_ + l0 + lr)) * 128 + 64 + nn];
  }
  float An[NST];
#pragma unroll
  for (int n = 0; n < NST; ++n) An[n] = -__expf(A_log[(size_t)d * 16 + n]);
  float z[NST], Pp[NST];
#pragma unroll
  for (int n = 0; n < NST; ++n) { z[n] = 0.f; Pp[n] = 1.f; }
  __syncthreads();
  const float*  dp = delta  + (size_t)(b * L_ + l0) * 2048 + d;
  const ushort* xp = hsc_pk + (size_t)(b * L_ + l0) * 4096 + d;
  for (int t = 0; t < LC; ++t) {
    float dl = dp[(size_t)t * 2048];
    float xv = bf2f(xp[(size_t)t * 4096]) + bf2f(xp[(size_t)t * 4096 + 2048]);
    float dx = dl * xv;
    const float* bc = &sBC[t * 32];
#pragma unroll
    for (int n = 0; n < NST; ++n) {
      float dA = __expf(dl * An[n]);
      z[n] = fmaf(dA, z[n], dx * bc[n]);
      Pp[n] *= dA;
    }
  }
  size_t base = ((size_t)(b * NCH + c) * 16) * 2048 + d;
#pragma unroll
  for (int n = 0; n < NST; ++n) {
    Pbuf[base + (size_t)n * 2048] = Pp[n];
    Qbuf[base + (size_t)n * 2048] = z[n];
  }
}

__global__ __launch_bounds__(256)
void scan_combine(const float* __restrict__ Pbuf, const float* __restrict__ Qbuf,
                  float* __restrict__ zinit)
{
  int i = blockIdx.x * 256 + threadIdx.x;   // B_*16*2048 = 65536
  int d = i & 2047, n = (i >> 11) & 15, b = i >> 15;
  float z = 0.f;
  for (int c = 0; c < NCH; ++c) {
    size_t idx = ((size_t)(b * NCH + c) * 16 + n) * 2048 + d;
    zinit[idx] = z;
    z = fmaf(Pbuf[idx], z, Qbuf[idx]);
  }
}

// pass2 overwrites hsc_pk in place with packed y (same thread, same addresses,
// read-before-write within each t iteration -> race-free by program order).
__global__ __launch_bounds__(256)
void scan_pass2(ushort* __restrict__ hsc_pk, const float* __restrict__ delta,
                const float* __restrict__ x_dbl, const float* __restrict__ A_log,
                const float* __restrict__ zinit, const float* __restrict__ Dvec,
                const float* __restrict__ hs_res)
{
  __shared__ float sBC[LC * 32];
  const int d = blockIdx.x * 256 + threadIdx.x;
  const int c = blockIdx.y, b = blockIdx.z;
  const int l0 = c * LC;
#pragma unroll
  for (int q = 0; q < 8; ++q) {
    int f = threadIdx.x + 256 * q;
    int lr = f >> 5, nn = f & 31;
    sBC[f] = x_dbl[((size_t)(b * L_ + l0 + lr)) * 128 + 64 + nn];
  }
  float An[NST];
#pragma unroll
  for (int n = 0; n < NST; ++n) An[n] = -__expf(A_log[(size_t)d * 16 + n]);
  float z[NST];
  size_t zb = ((size_t)(b * NCH + c) * 16) * 2048 + d;
#pragma unroll
  for (int n = 0; n < NST; ++n) z[n] = zinit[zb + (size_t)n * 2048];
  const float Dd = Dvec[d];
  __syncthreads();
  const float* dp = delta  + (size_t)(b * L_ + l0) * 2048 + d;
  ushort*      xp = hsc_pk + (size_t)(b * L_ + l0) * 4096 + d;
  const float* rp = hs_res + (size_t)(b * L_ + l0) * 4096 + 2048 + d;   // res half
  for (int t = 0; t < LC; ++t) {
    float dl = dp[(size_t)t * 2048];
    float xv = bf2f(xp[(size_t)t * 4096]) + bf2f(xp[(size_t)t * 4096 + 2048]);
    float dx = dl * xv;
    const float* bc = &sBC[t * 32];
    float y = 0.f;
#pragma unroll
    for (int n = 0; n < NST; ++n) {
      float dA = __expf(dl * An[n]);
      z[n] = fmaf(dA, z[n], dx * bc[n]);
      y = fmaf(z[n], bc[16 + n], y);
    }
    y = fmaf(xv, Dd, y);
    float rv = rp[(size_t)t * 4096];
    y *= rv / (1.f + __expf(-rv));        // * silu(res)
    ushort hi = f2bf(y), lo = f2bf(y - bf2f(hi));
    xp[(size_t)t * 4096] = hi;            // y_pk aliases hsc_pk (in place)
    xp[(size_t)t * 4096 + 2048] = lo;
  }
}

// ---------------- launch ----------------
extern "C" void kernel_launch(void* const* d_in, const int* in_sizes, int n_in,
                              void* d_out, int out_size, void* d_ws, size_t ws_size,
                              hipStream_t stream)
{
  (void)in_sizes; (void)n_in; (void)out_size; (void)ws_size;
  const float* hidden  = (const float*)d_in[0];
  const float* w_in    = (const float*)d_in[1];
  const float* w_conv  = (const float*)d_in[2];
  const float* w_xproj = (const float*)d_in[3];
  const float* w_dt    = (const float*)d_in[4];
  const float* b_dt    = (const float*)d_in[5];
  const float* A_log   = (const float*)d_in[6];
  const float* Dvec    = (const float*)d_in[7];
  const float* w_out   = (const float*)d_in[8];
  float* out = (float*)d_out;

  // ---- lifetime-aliased arena (peak ~173 MB, proven to fit) ----
  char* ws = (char*)d_ws;
  size_t off = 0;
  auto alloc = [&](size_t bytes) -> char* {
    char* p = ws + off; off += (bytes + 255) & ~(size_t)255; return p;
  };
  ushort* w_out_pk = (ushort*)alloc((size_t)1024 * 4096 * 2);   //  8 MB, whole call
  float*  hs_res   = (float*) alloc((size_t)4096 * 4096 * 4);   // 64 MB, GEMM1 -> pass2; then GEMM6 partials
  ushort* hsc_pk   = (ushort*)alloc((size_t)4096 * 4096 * 2);   // 32 MB, conv -> GEMM3/scans; pass2 rewrites as y_pk
  float*  delta    = (float*) alloc((size_t)4096 * 2048 * 4);   // 32 MB: GEMM3 partials | delta (GEMM4 -> scans)
  char*   regA     = alloc((size_t)16 * 1024 * 1024);           // 16 MB: hsin_pk | Pbuf+Qbuf
  char*   regB     = alloc((size_t)16 * 1024 * 1024);           // 16 MB: w_in_pk | zinit
  ushort* w_xproj_pk = (ushort*)alloc((size_t)128 * 4096 * 2);  //  1 MB
  ushort* w_dt_pk    = (ushort*)alloc((size_t)2048 * 128 * 2);  //  0.5 MB
  ushort* dt_pk      = (ushort*)alloc((size_t)4096 * 128 * 2);  //  1 MB
  float*  x_dbl      = (float*) alloc((size_t)4096 * 128 * 4);  //  2 MB

  ushort* hsin_pk   = (ushort*)regA;                 // pack -> GEMM1
  float*  Pbuf      = (float*)regA;                  // pass1 -> combine
  float*  Qbuf      = (float*)(regA + 8 * 1024 * 1024);
  ushort* w_in_pk   = (ushort*)regB;                 // pack -> GEMM1
  float*  zinit     = (float*)regB;                  // combine -> pass2
  float*  xdbl_part = delta;                         // GEMM3 partials (16 x 2MB), dead before GEMM4 writes delta
  float*  out_part  = hs_res;                        // GEMM6 partials (2 x 16MB), hs_res dead after pass2
  ushort* y_pk      = hsc_pk;                        // pass2 -> GEMM6

  auto packBlocks = [](int out_rows, int cols) { return (out_rows * (cols / 2) + 255) / 256; };

  // packs (weights + activations)
  pack_hilo<<<packBlocks(4096, 1024), 256, 0, stream>>>(hidden, hsin_pk, 4096, 1024, 1024, 4096);
  pack_hilo<<<packBlocks(4096, 1024), 256, 0, stream>>>(w_in, w_in_pk, 4096, 1024, 1024, 4096);
  pack_hilo<<<packBlocks(128, 2048), 256, 0, stream>>>(w_xproj, w_xproj_pk, 96, 2048, 2048, 128);
  pack_hilo<<<packBlocks(2048, 64), 256, 0, stream>>>(w_dt, w_dt_pk, 2048, 64, 64, 2048);
  pack_hilo<<<packBlocks(1024, 2048), 256, 0, stream>>>(w_out, w_out_pk, 1024, 2048, 2048, 1024);

  // 1) hs_res = hidden @ w_in^T   (M=4096, N=4096, K=1024)
  gemm_bt<0><<<dim3(32, 32, 1), 256, 0, stream>>>(hsin_pk, w_in_pk, hs_res, 4096, 4096, 1024, nullptr);

  // 2) conv + silu + pack
  conv_silu_pack<<<dim3(8, L_ / CONV_LT, B_), 256, 0, stream>>>(hs_res, w_conv, hsc_pk);

  // 3) x_dbl = hs @ w_xproj^T  (split-K=16 -> 512 blocks = 2/CU, then reduce + pack dt)
  gemm_bt<0><<<dim3(32, 1, 16), 256, 0, stream>>>(hsc_pk, w_xproj_pk, xdbl_part, 4096, 128, 2048, nullptr);
  reduce_xdbl<<<(4096 * 128) / 256, 256, 0, stream>>>(xdbl_part, x_dbl, dt_pk);

  // 4) delta = softplus(dt @ w_dt^T + b_dt)  (M=4096, N=2048, K=64)
  gemm_bt<1><<<dim3(32, 16, 1), 256, 0, stream>>>(dt_pk, w_dt_pk, delta, 4096, 2048, 64, b_dt);

  // 5) selective scan (two-pass chunked) + gate + pack y (in place over hsc_pk)
  scan_pass1<<<dim3(8, NCH, B_), 256, 0, stream>>>(hsc_pk, delta, x_dbl, A_log, Pbuf, Qbuf);
  scan_combine<<<(B_ * 16 * 2048) / 256, 256, 0, stream>>>(Pbuf, Qbuf, zinit);
  scan_pass2<<<dim3(8, NCH, B_), 256, 0, stream>>>(hsc_pk, delta, x_dbl, A_log, zinit, Dvec, hs_res);

  // 6) out = y @ w_out^T  (M=4096, N=1024, K=2048; split-K=2 -> 512 blocks = 2/CU)
  gemm_bt<0><<<dim3(32, 8, 2), 256, 0, stream>>>(y_pk, w_out_pk, out_part, 4096, 1024, 2048, nullptr);
  reduce2_out<<<(4096 * 1024 / 4) / 256, 256, 0, stream>>>(out_part, out);
}